// Round 2
// 1291.977 us; speedup vs baseline: 1.0749x; 1.0749x over previous
//
#include <hip/hip_runtime.h>
#include <hip/hip_bf16.h>

// ---------------------------------------------------------------------------
// NodeBlock: out = relu([seg_mean(edge_attrs,dst), node_attrs, g] @ W1 + b1) @ W2 + b2
//   1) counting-sort edges by dst -> CSR  (count, hierarchical scan, scatter)
//   2) gather-mean per node (coalesced 512B nontemporal edge reads, bf16 agg)
//   3) fused MLP with bf16 MFMA (16x16x32); global-attr part of W1 folded
//      into per-output bias gvec = g @ W1[256:384] + b1 (fp32, precomputed)
// ---------------------------------------------------------------------------

typedef __bf16 bf16x8 __attribute__((ext_vector_type(8)));
typedef float f32x4 __attribute__((ext_vector_type(4)));   // raw ext-vector: OK for nontemporal builtins
typedef unsigned short ushort4v __attribute__((ext_vector_type(4)));
typedef unsigned int uint4v __attribute__((ext_vector_type(4)));

__device__ inline unsigned short f2bf(float f) {
    unsigned int u = __float_as_uint(f);
    u = u + 0x7fffu + ((u >> 16) & 1u);   // round-to-nearest-even
    return (unsigned short)(u >> 16);
}

// ---------------- pass 1: count edges per node (int4-vectorized) ------------
__global__ __launch_bounds__(256) void count_kernel(const int* __restrict__ dst,
                                                    int* __restrict__ cnt, int E) {
    int t = blockIdx.x * 256 + threadIdx.x;
    int base = t * 4;
    if (base + 3 < E) {
        int4 d = *(const int4*)(dst + base);
        atomicAdd(&cnt[d.x], 1);
        atomicAdd(&cnt[d.y], 1);
        atomicAdd(&cnt[d.z], 1);
        atomicAdd(&cnt[d.w], 1);
    } else {
        for (int e = base; e < E; e++) atomicAdd(&cnt[dst[e]], 1);
    }
}

// ---------------- pass 2: hierarchical exclusive scan (3 stages) ------------
// S1: per-block (256 elems) sums
__global__ __launch_bounds__(256) void scan1_kernel(const int* __restrict__ cnt,
                                                    int* __restrict__ bsum, int n) {
    __shared__ int ws[4];
    int tid = threadIdx.x;
    int idx = blockIdx.x * 256 + tid;
    int v = (idx < n) ? cnt[idx] : 0;
    #pragma unroll
    for (int d = 32; d > 0; d >>= 1) v += __shfl_down(v, d, 64);
    if ((tid & 63) == 0) ws[tid >> 6] = v;
    __syncthreads();
    if (tid == 0) bsum[blockIdx.x] = ws[0] + ws[1] + ws[2] + ws[3];
}

// S2: exclusive scan of the (<=256) block sums, single tiny block
__global__ __launch_bounds__(256) void scan2_kernel(const int* __restrict__ bsum,
                                                    int* __restrict__ bscan, int nb) {
    __shared__ int ws[4];
    int tid = threadIdx.x;
    int lane = tid & 63, wv = tid >> 6;
    int v = (tid < nb) ? bsum[tid] : 0;
    int s = v;
    #pragma unroll
    for (int d = 1; d < 64; d <<= 1) {
        int t = __shfl_up(s, d, 64);
        if (lane >= d) s += t;
    }
    if (lane == 63) ws[wv] = s;
    __syncthreads();
    if (tid == 0) {
        int run = 0;
        #pragma unroll
        for (int j = 0; j < 4; j++) { int t = ws[j]; ws[j] = run; run += t; }
    }
    __syncthreads();
    int exc = s - v + ws[wv];
    if (tid < nb) bscan[tid] = exc;
}

// S3: final per-element exclusive scan + add block prefix
__global__ __launch_bounds__(256) void scan3_kernel(const int* __restrict__ cnt,
                                                    const int* __restrict__ bscan,
                                                    int* __restrict__ offs,
                                                    int* __restrict__ cursor, int n) {
    __shared__ int ws[4];
    int tid = threadIdx.x;
    int idx = blockIdx.x * 256 + tid;
    int lane = tid & 63, wv = tid >> 6;
    int v = (idx < n) ? cnt[idx] : 0;
    int s = v;
    #pragma unroll
    for (int d = 1; d < 64; d <<= 1) {
        int t = __shfl_up(s, d, 64);
        if (lane >= d) s += t;
    }
    if (lane == 63) ws[wv] = s;
    __syncthreads();
    if (tid == 0) {
        int run = 0;
        #pragma unroll
        for (int j = 0; j < 4; j++) { int t = ws[j]; ws[j] = run; run += t; }
    }
    __syncthreads();
    int exc = s - v + ws[wv] + bscan[blockIdx.x];
    if (idx < n) { offs[idx] = exc; cursor[idx] = exc; }
}

// ---------------- pass 3: scatter edge ids into CSR (int4-vectorized) -------
__global__ __launch_bounds__(256) void scatter_kernel(const int* __restrict__ dst,
                                                      int* __restrict__ cursor,
                                                      int* __restrict__ eidl, int E) {
    int t = blockIdx.x * 256 + threadIdx.x;
    int base = t * 4;
    if (base + 3 < E) {
        int4 d = *(const int4*)(dst + base);
        int p0 = atomicAdd(&cursor[d.x], 1);
        int p1 = atomicAdd(&cursor[d.y], 1);
        int p2 = atomicAdd(&cursor[d.z], 1);
        int p3 = atomicAdd(&cursor[d.w], 1);
        eidl[p0] = base;
        eidl[p1] = base + 1;
        eidl[p2] = base + 2;
        eidl[p3] = base + 3;
    } else {
        for (int e = base; e < E; e++) {
            int p = atomicAdd(&cursor[dst[e]], 1);
            eidl[p] = e;
        }
    }
}

// ---------------- weight prep: transpose->bf16, fold global into bias ------
__global__ __launch_bounds__(256) void prep_kernel(const float* __restrict__ W1,
                                                   const float* __restrict__ b1,
                                                   const float* __restrict__ W2,
                                                   const float* __restrict__ g,
                                                   unsigned short* __restrict__ W1t,
                                                   unsigned short* __restrict__ W2t,
                                                   float* __restrict__ gvec) {
    int tid = blockIdx.x * blockDim.x + threadIdx.x;
    int stride = gridDim.x * blockDim.x;
    // W1t[n][k] = W1[k][n], k in [0,256) (agg+node parts), bf16, row stride 256
    for (int i = tid; i < 128 * 256; i += stride) {
        int n = i >> 8, k = i & 255;
        W1t[i] = f2bf(W1[k * 128 + n]);
    }
    // W2t[n][k] = W2[k][n], bf16, row stride 128
    for (int i = tid; i < 128 * 128; i += stride) {
        int n = i >> 7, k = i & 127;
        W2t[i] = f2bf(W2[k * 128 + n]);
    }
    // gvec[n] = b1[n] + sum_k g[k] * W1[(256+k)][n]   (fp32, exact part)
    if (tid < 128) {
        float s = b1[tid];
        for (int k = 0; k < 128; k++) s += g[k] * W1[(256 + k) * 128 + tid];
        gvec[tid] = s;
    }
}

// ---------------- pass 4: gather-mean per node (bf16 output) ----------------
// thread = (node, float4 chunk c of 32). 32 lanes of a node read one 512B edge
// row fully coalesced. Edge rows are read exactly once -> nontemporal.
__global__ __launch_bounds__(256) void gather_kernel(const float* __restrict__ edge_attrs,
                                                     const int* __restrict__ eidl,
                                                     const int* __restrict__ offs,
                                                     const int* __restrict__ cnt,
                                                     unsigned short* __restrict__ aggbf,
                                                     int n_nodes) {
    int gid = blockIdx.x * 256 + threadIdx.x;
    int n = gid >> 5, c = gid & 31;
    if (n >= n_nodes) return;
    int off = offs[n];
    int deg = cnt[n];
    const f32x4* ea = (const f32x4*)edge_attrs;
    float ax = 0.f, ay = 0.f, az = 0.f, aw = 0.f;
    int i = 0;
    for (; i + 8 <= deg; i += 8) {
        int e[8];
        #pragma unroll
        for (int j = 0; j < 8; j++) e[j] = eidl[off + i + j];
        #pragma unroll
        for (int j = 0; j < 8; j++) {
            f32x4 v = __builtin_nontemporal_load(&ea[e[j] * 32 + c]);
            ax += v.x; ay += v.y; az += v.z; aw += v.w;
        }
    }
    for (; i + 4 <= deg; i += 4) {
        int e0 = eidl[off + i], e1 = eidl[off + i + 1];
        int e2 = eidl[off + i + 2], e3 = eidl[off + i + 3];
        f32x4 v0 = __builtin_nontemporal_load(&ea[e0 * 32 + c]);
        f32x4 v1 = __builtin_nontemporal_load(&ea[e1 * 32 + c]);
        f32x4 v2 = __builtin_nontemporal_load(&ea[e2 * 32 + c]);
        f32x4 v3 = __builtin_nontemporal_load(&ea[e3 * 32 + c]);
        ax += v0.x + v1.x + v2.x + v3.x;
        ay += v0.y + v1.y + v2.y + v3.y;
        az += v0.z + v1.z + v2.z + v3.z;
        aw += v0.w + v1.w + v2.w + v3.w;
    }
    for (; i < deg; i++) {
        int e = eidl[off + i];
        f32x4 v = __builtin_nontemporal_load(&ea[e * 32 + c]);
        ax += v.x; ay += v.y; az += v.z; aw += v.w;
    }
    float inv = 1.0f / fmaxf((float)deg, 1.0f);
    ushort4v u;
    u.x = f2bf(ax * inv); u.y = f2bf(ay * inv);
    u.z = f2bf(az * inv); u.w = f2bf(aw * inv);
    // 8B per lane, 256B per node row, coalesced
    *(ushort4v*)(aggbf + n * 128 + c * 4) = u;
}

// ---------------- pass 5: fused MLP with bf16 MFMA -------------------------
// Block: 256 threads = 4 waves, 64 nodes. Wave w owns node rows [w*16, w*16+16).
// GEMM1: [64 x 256] @ [256 x 128] -> relu(+gvec) -> GEMM2: [64 x 128] @ [128 x 128]
#define LDH 264   // 256 + 8 pad (ushort) -> 528B rows (16B-aligned), 2-way bank alias
#define LDY 136   // 128 + 8 pad (ushort) -> 272B rows
__global__ __launch_bounds__(256) void mlp_kernel(const unsigned short* __restrict__ aggbf,
                                                  const float* __restrict__ node_attrs,
                                                  const unsigned short* __restrict__ W1t,
                                                  const unsigned short* __restrict__ W2t,
                                                  const float* __restrict__ gvec,
                                                  const float* __restrict__ b2,
                                                  float* __restrict__ out, int n_nodes) {
    __shared__ unsigned short lds_h[64 * LDH];
    __shared__ unsigned short lds_y[64 * LDY];
    int tid = threadIdx.x;
    int n0 = blockIdx.x * 64;

    // stage cols [0,128) from aggbf: raw bf16 copy, 16B per thread-iter
    for (int i = tid; i < 64 * 16; i += 256) {
        int r = i >> 4, c8 = i & 15;
        int node = n0 + r;
        uint4v u = (uint4v){0u, 0u, 0u, 0u};
        if (node < n_nodes) u = ((const uint4v*)aggbf)[node * 16 + c8];
        *(uint4v*)(lds_h + r * LDH + c8 * 8) = u;
    }
    // stage cols [128,256) from node_attrs: fp32 -> bf16 (read-once -> nt)
    for (int i = tid; i < 64 * 32; i += 256) {
        int r = i >> 5, c4 = i & 31;
        int node = n0 + r;
        f32x4 v = (f32x4){0.f, 0.f, 0.f, 0.f};
        if (node < n_nodes) v = __builtin_nontemporal_load(&((const f32x4*)node_attrs)[node * 32 + c4]);
        ushort4v u;
        u.x = f2bf(v.x); u.y = f2bf(v.y); u.z = f2bf(v.z); u.w = f2bf(v.w);
        *(ushort4v*)(lds_h + r * LDH + 128 + c4 * 4) = u;
    }
    __syncthreads();

    int lane = tid & 63;
    int w = tid >> 6;
    int lrow = lane & 15;
    int quad = lane >> 4;
    int m = w * 16 + lrow;   // A-fragment row (node within tile)

    f32x4 acc[8];
    #pragma unroll
    for (int i = 0; i < 8; i++) acc[i] = (f32x4){0.f, 0.f, 0.f, 0.f};

    // GEMM1: K = 256 (8 steps of 32)
    #pragma unroll
    for (int ks = 0; ks < 8; ks++) {
        bf16x8 a = *(const bf16x8*)(lds_h + m * LDH + ks * 32 + quad * 8);
        const unsigned short* bp = W1t + lrow * 256 + ks * 32 + quad * 8;
        #pragma unroll
        for (int nb = 0; nb < 8; nb++) {
            bf16x8 b = *(const bf16x8*)(bp + nb * 16 * 256);
            acc[nb] = __builtin_amdgcn_mfma_f32_16x16x32_bf16(a, b, acc[nb], 0, 0, 0);
        }
    }

    // relu(acc + gvec) -> lds_y (bf16), C layout: row = w*16+quad*4+reg, col = nb*16+lrow
    #pragma unroll
    for (int nb = 0; nb < 8; nb++) {
        int n = nb * 16 + lrow;
        float gv = gvec[n];
        #pragma unroll
        for (int reg = 0; reg < 4; reg++) {
            int row = w * 16 + quad * 4 + reg;
            float y = fmaxf(acc[nb][reg] + gv, 0.f);
            lds_y[row * LDY + n] = f2bf(y);
        }
    }
    __syncthreads();

    f32x4 acc2[8];
    #pragma unroll
    for (int i = 0; i < 8; i++) acc2[i] = (f32x4){0.f, 0.f, 0.f, 0.f};

    // GEMM2: K = 128 (4 steps of 32)
    #pragma unroll
    for (int ks = 0; ks < 4; ks++) {
        bf16x8 a = *(const bf16x8*)(lds_y + m * LDY + ks * 32 + quad * 8);
        const unsigned short* bp = W2t + lrow * 128 + ks * 32 + quad * 8;
        #pragma unroll
        for (int nb = 0; nb < 8; nb++) {
            bf16x8 b = *(const bf16x8*)(bp + nb * 16 * 128);
            acc2[nb] = __builtin_amdgcn_mfma_f32_16x16x32_bf16(a, b, acc2[nb], 0, 0, 0);
        }
    }

    // epilogue: out = acc2 + b2 (write-once -> nt store)
    #pragma unroll
    for (int nb = 0; nb < 8; nb++) {
        int n = nb * 16 + lrow;
        float bb = b2[n];
        #pragma unroll
        for (int reg = 0; reg < 4; reg++) {
            int row = w * 16 + quad * 4 + reg;
            int node = n0 + row;
            if (node < n_nodes)
                __builtin_nontemporal_store(acc2[nb][reg] + bb, &out[node * 128 + n]);
        }
    }
}

// ---------------------------------------------------------------------------
extern "C" void kernel_launch(void* const* d_in, const int* in_sizes, int n_in,
                              void* d_out, int out_size, void* d_ws, size_t ws_size,
                              hipStream_t stream) {
    const float* edge_attrs  = (const float*)d_in[0];
    const float* node_attrs  = (const float*)d_in[1];
    const float* global_attr = (const float*)d_in[2];
    const float* W1 = (const float*)d_in[3];
    const float* b1 = (const float*)d_in[4];
    const float* W2 = (const float*)d_in[5];
    const float* b2 = (const float*)d_in[6];
    const int* edge_dst = (const int*)d_in[7];

    int E = in_sizes[0] / 128;
    int N = in_sizes[1] / 128;

    char* ws = (char*)d_ws;
    int* cnt    = (int*)ws;                       // N ints (200 KB)
    int* offs   = (int*)(ws + 0x40000);           // N ints
    int* cursor = (int*)(ws + 0x80000);           // N ints
    int* eidl   = (int*)(ws + 0xC0000);           // E ints (6.4 MB)
    unsigned short* W1t = (unsigned short*)(ws + 0x800000);  // 64 KB
    unsigned short* W2t = (unsigned short*)(ws + 0x810000);  // 32 KB
    float* gvec = (float*)(ws + 0x818000);        // 512 B
    int* bsum   = (int*)(ws + 0x820000);          // <=256 ints
    int* bscan  = (int*)(ws + 0x821000);          // <=256 ints
    unsigned short* aggbf = (unsigned short*)(ws + 0x900000); // N*128 bf16 (12.8 MB)

    float* out = (float*)d_out;

    int NB = (N + 255) / 256;   // scan blocks (196 for N=50000, must be <=256)

    hipMemsetAsync(cnt, 0, N * sizeof(int), stream);
    count_kernel<<<(E / 4 + 255) / 256, 256, 0, stream>>>(edge_dst, cnt, E);
    scan1_kernel<<<NB, 256, 0, stream>>>(cnt, bsum, N);
    scan2_kernel<<<1, 256, 0, stream>>>(bsum, bscan, NB);
    scan3_kernel<<<NB, 256, 0, stream>>>(cnt, bscan, offs, cursor, N);
    scatter_kernel<<<(E / 4 + 255) / 256, 256, 0, stream>>>(edge_dst, cursor, eidl, E);
    prep_kernel<<<64, 256, 0, stream>>>(W1, b1, W2, global_attr, W1t, W2t, gvec);
    gather_kernel<<<(N * 32 + 255) / 256, 256, 0, stream>>>(edge_attrs, eidl, offs, cnt, aggbf, N);
    mlp_kernel<<<(N + 63) / 64, 256, 0, stream>>>(aggbf, node_attrs, W1t, W2t, gvec, b2, out, N);
}